// Round 1
// baseline (96.909 us; speedup 1.0000x reference)
//
#include <hip/hip_runtime.h>
#include <math.h>

// riemannian_exp: out[b] = key_poses[argmax(ybin[b])] @ Rodrigues(yres[b])
// B = 1048576, C = 100. Memory-bound on the ybin read (419 MB).

__global__ __launch_bounds__(256) void rexp_kernel(
    const float* __restrict__ ybin,      // [B, C]
    const float* __restrict__ yres,      // [B, 3]
    const float* __restrict__ key_poses, // [C, 3, 3]
    float* __restrict__ out,             // [B, 3, 3]
    int B, int C)
{
    // Stage key_poses (C*9 = 900 floats = 3.6 KB) into LDS once per block.
    __shared__ float kp[1024];
    const int kpN = C * 9;
    for (int i = threadIdx.x; i < kpN; i += blockDim.x) kp[i] = key_poses[i];
    __syncthreads();

    int b = blockIdx.x * blockDim.x + threadIdx.x;
    if (b >= B) return;

    // ---- argmax over 100 logits via 25 float4 loads (row is 16B-aligned) ----
    const float4* row = reinterpret_cast<const float4*>(ybin + (size_t)b * (size_t)C);
    float best = -INFINITY;
    int bi = 0;
    #pragma unroll
    for (int j = 0; j < 25; ++j) {
        float4 v = row[j];
        if (v.x > best) { best = v.x; bi = j * 4 + 0; }
        if (v.y > best) { best = v.y; bi = j * 4 + 1; }
        if (v.z > best) { best = v.z; bi = j * 4 + 2; }
        if (v.w > best) { best = v.w; bi = j * 4 + 3; }
    }

    // ---- Rodrigues ----
    float rx = yres[(size_t)b * 3 + 0];
    float ry = yres[(size_t)b * 3 + 1];
    float rz = yres[(size_t)b * 3 + 2];
    float angle = sqrtf(rx * rx + ry * ry + rz * rz);
    float inv = 1.0f / fmaxf(angle, 1e-12f);
    float ax = rx * inv, ay = ry * inv, az = rz * inv;
    float s, cosv;
    sincosf(angle, &s, &cosv);
    float c = 1.0f - cosv;

    // K = [[0,-az,ay],[az,0,-ax],[-ay,ax,0]]
    // KK = a a^T - |a|^2 I  (expanded literally, matches reference K@K)
    float axx = ax * ax, ayy = ay * ay, azz = az * az;
    float axy = ax * ay, axz = ax * az, ayz = ay * az;

    float R00 = 1.0f + c * (-ayy - azz);
    float R01 = -s * az + c * axy;
    float R02 =  s * ay + c * axz;
    float R10 =  s * az + c * axy;
    float R11 = 1.0f + c * (-axx - azz);
    float R12 = -s * ax + c * ayz;
    float R20 = -s * ay + c * axz;
    float R21 =  s * ax + c * ayz;
    float R22 = 1.0f + c * (-axx - ayy);

    // ---- out = key_poses[bi] @ R ----
    const float* P = &kp[bi * 9];
    float P00 = P[0], P01 = P[1], P02 = P[2];
    float P10 = P[3], P11 = P[4], P12 = P[5];
    float P20 = P[6], P21 = P[7], P22 = P[8];

    float* o = out + (size_t)b * 9;
    o[0] = P00 * R00 + P01 * R10 + P02 * R20;
    o[1] = P00 * R01 + P01 * R11 + P02 * R21;
    o[2] = P00 * R02 + P01 * R12 + P02 * R22;
    o[3] = P10 * R00 + P11 * R10 + P12 * R20;
    o[4] = P10 * R01 + P11 * R11 + P12 * R21;
    o[5] = P10 * R02 + P11 * R12 + P12 * R22;
    o[6] = P20 * R00 + P21 * R10 + P22 * R20;
    o[7] = P20 * R01 + P21 * R11 + P22 * R21;
    o[8] = P20 * R02 + P21 * R12 + P22 * R22;
}

extern "C" void kernel_launch(void* const* d_in, const int* in_sizes, int n_in,
                              void* d_out, int out_size, void* d_ws, size_t ws_size,
                              hipStream_t stream) {
    const float* ybin      = (const float*)d_in[0];
    const float* yres      = (const float*)d_in[1];
    const float* key_poses = (const float*)d_in[2];
    float* out = (float*)d_out;

    int B = in_sizes[1] / 3;
    int C = in_sizes[0] / B;

    int block = 256;
    int grid = (B + block - 1) / block;
    rexp_kernel<<<grid, block, 0, stream>>>(ybin, yres, key_poses, out, B, C);
}

// Round 2
// 95.905 us; speedup vs baseline: 1.0105x; 1.0105x over previous
//
#include <hip/hip_runtime.h>
#include <math.h>

// riemannian_exp: out[b] = key_poses[argmax(ybin[b])] @ Rodrigues(yres[b])
// B = 1048576, C = 100 (hard assumption C==100 in fast path).
// Memory-bound on the ybin read (419 MB). Strategy: coalesced cooperative
// argmax (4 lanes/row, 64B contiguous per group per load), LDS-staged
// yres/out for coalesced edge traffic.

#define ROWS_PER_BLOCK 256

__global__ __launch_bounds__(256) void rexp_fast_kernel(
    const float* __restrict__ ybin,      // [B, 100]
    const float* __restrict__ yres,      // [B, 3]
    const float* __restrict__ key_poses, // [100, 3, 3]
    float* __restrict__ out)             // [B, 3, 3]
{
    __shared__ float kp[912];      // 100*9 key poses
    __shared__ int   s_bi[256];    // argmax index per row
    __shared__ float s_yres[768];  // 256*3 staged residuals
    __shared__ float s_out[2304];  // 256*9 staged outputs

    const int tid = threadIdx.x;
    const long long row0 = (long long)blockIdx.x * ROWS_PER_BLOCK;

    // stage key_poses (3.6 KB, coalesced)
    for (int i = tid; i < 900; i += 256) kp[i] = key_poses[i];

    // stage yres coalesced: 768 floats = 192 float4
    {
        const float4* src = reinterpret_cast<const float4*>(yres + row0 * 3);
        float4* dst = reinterpret_cast<float4*>(s_yres);
        if (tid < 192) dst[tid] = src[tid];
    }

    // ---- phase 1: cooperative argmax, 4 lanes per row ----
    const int lane4 = tid & 3;
    const int rloc  = tid >> 2;   // 0..63
    #pragma unroll 1
    for (int t = 0; t < 4; ++t) {
        const long long row = row0 + t * 64 + rloc;
        const float4* rbase = reinterpret_cast<const float4*>(ybin + row * 100);
        float best = -INFINITY;
        int bi = 0;
        #pragma unroll
        for (int j = 0; j < 7; ++j) {
            int c = lane4 + j * 4;          // float4 chunk index within row
            if (c < 25) {
                float4 v = rbase[c];        // groups of 4 lanes cover 64B contiguous
                int i0 = c * 4;
                if (v.x > best) { best = v.x; bi = i0;     }
                if (v.y > best) { best = v.y; bi = i0 + 1; }
                if (v.z > best) { best = v.z; bi = i0 + 2; }
                if (v.w > best) { best = v.w; bi = i0 + 3; }
            }
        }
        // reduce (max, first index) across the 4-lane group
        #pragma unroll
        for (int m = 1; m <= 2; m <<= 1) {
            float ob = __shfl_xor(best, m);
            int   oi = __shfl_xor(bi, m);
            if (ob > best || (ob == best && oi < bi)) { best = ob; bi = oi; }
        }
        if (lane4 == 0) s_bi[t * 64 + rloc] = bi;
    }
    __syncthreads();

    // ---- phase 2: one thread per row, all from LDS ----
    {
        int bi = s_bi[tid];
        float rx = s_yres[tid * 3 + 0];
        float ry = s_yres[tid * 3 + 1];
        float rz = s_yres[tid * 3 + 2];
        float angle = sqrtf(rx * rx + ry * ry + rz * rz);
        float inv = 1.0f / fmaxf(angle, 1e-12f);
        float ax = rx * inv, ay = ry * inv, az = rz * inv;
        float s, cosv;
        sincosf(angle, &s, &cosv);
        float c = 1.0f - cosv;

        float axx = ax * ax, ayy = ay * ay, azz = az * az;
        float axy = ax * ay, axz = ax * az, ayz = ay * az;

        float R00 = 1.0f + c * (-ayy - azz);
        float R01 = -s * az + c * axy;
        float R02 =  s * ay + c * axz;
        float R10 =  s * az + c * axy;
        float R11 = 1.0f + c * (-axx - azz);
        float R12 = -s * ax + c * ayz;
        float R20 = -s * ay + c * axz;
        float R21 =  s * ax + c * ayz;
        float R22 = 1.0f + c * (-axx - ayy);

        const float* P = &kp[bi * 9];
        float P00 = P[0], P01 = P[1], P02 = P[2];
        float P10 = P[3], P11 = P[4], P12 = P[5];
        float P20 = P[6], P21 = P[7], P22 = P[8];

        float* o = &s_out[tid * 9];
        o[0] = P00 * R00 + P01 * R10 + P02 * R20;
        o[1] = P00 * R01 + P01 * R11 + P02 * R21;
        o[2] = P00 * R02 + P01 * R12 + P02 * R22;
        o[3] = P10 * R00 + P11 * R10 + P12 * R20;
        o[4] = P10 * R01 + P11 * R11 + P12 * R21;
        o[5] = P10 * R02 + P11 * R12 + P12 * R22;
        o[6] = P20 * R00 + P21 * R10 + P22 * R20;
        o[7] = P20 * R01 + P21 * R11 + P22 * R21;
        o[8] = P20 * R02 + P21 * R12 + P22 * R22;
    }
    __syncthreads();

    // ---- coalesced store: 2304 floats = 576 float4 ----
    {
        float4* dst = reinterpret_cast<float4*>(out + row0 * 9);
        const float4* src = reinterpret_cast<const float4*>(s_out);
        dst[tid]       = src[tid];
        dst[tid + 256] = src[tid + 256];
        if (tid < 64) dst[tid + 512] = src[tid + 512];
    }
}

// Tail kernel for B % 256 rows (not used when B == 1048576, but kept general).
__global__ void rexp_tail_kernel(
    const float* __restrict__ ybin, const float* __restrict__ yres,
    const float* __restrict__ key_poses, float* __restrict__ out,
    int B, int C, int start)
{
    int b = start + blockIdx.x * blockDim.x + threadIdx.x;
    if (b >= B) return;
    const float* row = ybin + (size_t)b * C;
    float best = -INFINITY; int bi = 0;
    for (int j = 0; j < C; ++j) if (row[j] > best) { best = row[j]; bi = j; }
    float rx = yres[(size_t)b*3], ry = yres[(size_t)b*3+1], rz = yres[(size_t)b*3+2];
    float angle = sqrtf(rx*rx + ry*ry + rz*rz);
    float inv = 1.0f / fmaxf(angle, 1e-12f);
    float ax = rx*inv, ay = ry*inv, az = rz*inv;
    float s, cosv; sincosf(angle, &s, &cosv);
    float c = 1.0f - cosv;
    float axx=ax*ax, ayy=ay*ay, azz=az*az, axy=ax*ay, axz=ax*az, ayz=ay*az;
    float R00=1.0f+c*(-ayy-azz), R01=-s*az+c*axy, R02= s*ay+c*axz;
    float R10= s*az+c*axy, R11=1.0f+c*(-axx-azz), R12=-s*ax+c*ayz;
    float R20=-s*ay+c*axz, R21= s*ax+c*ayz, R22=1.0f+c*(-axx-ayy);
    const float* P = key_poses + bi * 9;
    float* o = out + (size_t)b * 9;
    o[0]=P[0]*R00+P[1]*R10+P[2]*R20; o[1]=P[0]*R01+P[1]*R11+P[2]*R21; o[2]=P[0]*R02+P[1]*R12+P[2]*R22;
    o[3]=P[3]*R00+P[4]*R10+P[5]*R20; o[4]=P[3]*R01+P[4]*R11+P[5]*R21; o[5]=P[3]*R02+P[4]*R12+P[5]*R22;
    o[6]=P[6]*R00+P[7]*R10+P[8]*R20; o[7]=P[6]*R01+P[7]*R11+P[8]*R21; o[8]=P[6]*R02+P[7]*R12+P[8]*R22;
}

extern "C" void kernel_launch(void* const* d_in, const int* in_sizes, int n_in,
                              void* d_out, int out_size, void* d_ws, size_t ws_size,
                              hipStream_t stream) {
    const float* ybin      = (const float*)d_in[0];
    const float* yres      = (const float*)d_in[1];
    const float* key_poses = (const float*)d_in[2];
    float* out = (float*)d_out;

    int B = in_sizes[1] / 3;
    int C = in_sizes[0] / B;   // == 100 for this problem

    if (C == 100) {
        int fullBlocks = B / ROWS_PER_BLOCK;
        if (fullBlocks > 0)
            rexp_fast_kernel<<<fullBlocks, 256, 0, stream>>>(ybin, yres, key_poses, out);
        int rem = B - fullBlocks * ROWS_PER_BLOCK;
        if (rem > 0) {
            int start = fullBlocks * ROWS_PER_BLOCK;
            rexp_tail_kernel<<<(rem + 255) / 256, 256, 0, stream>>>(
                ybin, yres, key_poses, out, B, C, start);
        }
    } else {
        rexp_tail_kernel<<<(B + 255) / 256, 256, 0, stream>>>(
            ybin, yres, key_poses, out, B, C, 0);
    }
}